// Round 6
// baseline (382.904 us; speedup 1.0000x reference)
//
#include <hip/hip_runtime.h>
#include <stdint.h>

// Problem constants
#define M_TOT 8192      // B*N = 4*2048 rows
#define N_TOT 16384     // out_dim = 2*128*64
#define K_TOT 1024      // HIDDEN

typedef __bf16 bf16x8 __attribute__((ext_vector_type(8)));
typedef float f32x4 __attribute__((ext_vector_type(4)));

__device__ __forceinline__ unsigned short f2bf(float f) {
  unsigned int u = __float_as_uint(f);
  u = u + 0x7FFFu + ((u >> 16) & 1u);   // RNE
  return (unsigned short)(u >> 16);
}

__device__ __forceinline__ void gload_lds16(const void* g, void* l) {
  __builtin_amdgcn_global_load_lds(
      (const __attribute__((address_space(1))) unsigned int*)g,
      (__attribute__((address_space(3))) unsigned int*)l,
      16, 0, 0);
}

// ---- prep kernel 1: node f32 -> bf16, 32 elems/thread, 1024 blocks ----
__global__ __launch_bounds__(256) void k_convert_node(
    const float* __restrict__ src, unsigned short* __restrict__ dst) {
  size_t base = ((size_t)blockIdx.x * 256 + threadIdx.x) * 8;
#pragma unroll
  for (int it = 0; it < 4; it++) {
    size_t i = base + (size_t)it * (1024 * 256 * 8);
    float4 v0 = *(const float4*)(src + i);
    float4 v1 = *(const float4*)(src + i + 4);
    union { unsigned short u[8]; uint4 q; } r;
    r.u[0] = f2bf(v0.x); r.u[1] = f2bf(v0.y); r.u[2] = f2bf(v0.z); r.u[3] = f2bf(v0.w);
    r.u[4] = f2bf(v1.x); r.u[5] = f2bf(v1.y); r.u[6] = f2bf(v1.z); r.u[7] = f2bf(v1.w);
    *(uint4*)(dst + i) = r.q;
  }
}

// ---- prep kernel 2: W [K][O] f32 -> Wt [O][K] bf16, 64x64 tiles ----
__global__ __launch_bounds__(256) void k_transpose_w(
    const float* __restrict__ W, unsigned short* __restrict__ Wt) {
  __shared__ float tile[64][65];
  int o0 = blockIdx.x * 64;
  int k0 = blockIdx.y * 64;
  int t = threadIdx.x;
  int kr0 = t >> 4, c4 = t & 15;
#pragma unroll
  for (int i = 0; i < 4; i++) {
    int kr = kr0 + i * 16;
    float4 v = *(const float4*)&W[(size_t)(k0 + kr) * N_TOT + o0 + c4 * 4];
    tile[kr][c4 * 4 + 0] = v.x;
    tile[kr][c4 * 4 + 1] = v.y;
    tile[kr][c4 * 4 + 2] = v.z;
    tile[kr][c4 * 4 + 3] = v.w;
  }
  __syncthreads();
  int or0 = t >> 3, c8 = t & 7;
#pragma unroll
  for (int i = 0; i < 2; i++) {
    int orr = or0 + i * 32;
    union { unsigned short u[8]; uint4 q; } r;
#pragma unroll
    for (int j = 0; j < 8; j++) r.u[j] = f2bf(tile[c8 * 8 + j][orr]);
    *(uint4*)&Wt[(size_t)(o0 + orr) * K_TOT + k0 + c8 * 8] = r.q;
  }
}

// ---- prep kernel 3: sin/cos tables [row=8192][d=32] ----
__global__ __launch_bounds__(256) void k_sincos(
    const float* __restrict__ mass, float* __restrict__ sin_t, float* __restrict__ cos_t) {
  int t = blockIdx.x * 256 + threadIdx.x;   // 0..262143
  int row = t >> 5;
  int d = t & 31;
  float m = mass[row];
  float invf = expf(-0.28782313662425575f * (float)d);  // ln(10000)/32
  float ang = m * invf;
  float s, c;
  sincosf(ang, &s, &c);
  sin_t[t] = s;
  cos_t[t] = c;
}

// ---- main GEMM: 256x128 tile, BK=32, 4 waves (2x2), 3-deep pipelined LDS,
//      counted vmcnt (T3+T4), setprio (T5), XCD swizzle (T1), 2 blocks/CU.
//      LDS XOR-swizzle (T2, both-sides): logical (row,kslot) stored at
//      byte (row>>1)*128 + ((((row&1)*4+kslot)^((row>>1)&7)))*16.
//      Dest stays linear for global_load_lds; SOURCE is pre-permuted
//      (within the same 64B row segment -> zero coalescing cost). ----
__global__ __launch_bounds__(256, 2) void k_gemm256b(
    const unsigned short* __restrict__ A,    // [8192][1024] bf16
    const unsigned short* __restrict__ Bt,   // [16384][1024] bf16 (W^T)
    const float* __restrict__ bias,          // [16384]
    const float* __restrict__ sin_t,         // [8192][32]
    const float* __restrict__ cos_t,
    float* __restrict__ out)                 // [2][4][128][2048][64]
{
  extern __shared__ char smem[];   // 3 bufs x (As 16KB + Bs 8KB) = 72 KiB

  int tid  = threadIdx.x;
  int lane = tid & 63;
  int wid  = tid >> 6;      // 0..3
  int wm   = wid >> 1;      // 0..1  (M half: 128 rows)
  int wn   = wid & 1;       // 0..1  (N half: 64 cols)

  // XCD-bijective swizzle: 4096 blocks, 4096 % 8 == 0, chunk = 512
  int orig = blockIdx.x;
  int wg = (orig & 7) * 512 + (orig >> 3);
  int bn0 = (wg & 127) * 128;
  int bm0 = (wg >> 7) * 256;

  // staging with inverse-swizzled source:
  // chunk c = j*256 + tid: rowp = c>>3, s' = c&7, v = s' ^ (rowp&7),
  // row = (rowp<<1)+(v>>2) = j*64 + (tid>>3)*2 + (v>>2), kslot = v&3.
  int sv   = (tid & 7) ^ ((tid >> 3) & 7);
  int arow = ((tid >> 3) << 1) + (sv >> 2);
  int kst  = sv & 3;
  const unsigned short* srcA = A  + (size_t)(bm0 + arow) * K_TOT + kst * 8;
  const unsigned short* srcB = Bt + (size_t)(bn0 + arow) * K_TOT + kst * 8;
  const size_t rs64 = (size_t)64 * K_TOT;

  // wave-uniform LDS staging bases: A at buf+0 (16KB), B at buf+16384 (8KB)
  int wofs = wid * 1024;

#define STAGE_A(s_, bo_) do { char* dA = smem + (bo_) + wofs; \
    const unsigned short* sa = srcA + (size_t)(s_) * 32; \
    gload_lds16(sa,            dA); \
    gload_lds16(sa + rs64,     dA + 4096); \
    gload_lds16(sa + 2 * rs64, dA + 8192); \
    gload_lds16(sa + 3 * rs64, dA + 12288); } while (0)
#define STAGE_B(s_, bo_) do { char* dB = smem + (bo_) + 16384 + wofs; \
    const unsigned short* sb = srcB + (size_t)(s_) * 32; \
    gload_lds16(sb,        dB); \
    gload_lds16(sb + rs64, dB + 4096); } while (0)

  // prologue: prefetch K-tiles 0,1 (12 loads in flight per wave)
  STAGE_A(0, 0); STAGE_B(0, 0);
  STAGE_A(1, 24576); STAGE_B(1, 24576);

  f32x4 acc[8][4] = {};

  int r = lane & 15;        // frag row/col within 16
  int q = lane >> 4;        // k-chunk 0..3 (8 bf16 each)
  // swizzled read offsets: lane reads (row = base + r, kslot = q)
  // byte = (row>>1)*128 + (((r&1)*4+q) ^ ((r>>1)&7))*16  (+ mi/ni * 1024)
  int sl   = (((r & 1) << 2) + q) ^ ((r >> 1) & 7);
  int aoff = wm * 8192 + (r >> 1) * 128 + sl * 16;   // byte offset in As
  int boff = wn * 4096 + (r >> 1) * 128 + sl * 16;   // byte offset in Bs

  int cur = 0;              // buf byte offsets rotate 0 -> 24576 -> 49152
  int stg = 49152;          // stage target for tile s+2 = buf (s-1)%3

  for (int s = 0; s < 32; ++s) {
    if (s < 31) { asm volatile("s_waitcnt vmcnt(6)" ::: "memory"); }
    else        { asm volatile("s_waitcnt vmcnt(0)" ::: "memory"); }
    __builtin_amdgcn_s_barrier();          // raw barrier: no vmcnt(0) drain
    __builtin_amdgcn_sched_barrier(0);     // keep ds_reads below the barrier

    const char* As_ = smem + cur;
    const char* Bs_ = As_ + 16384;

    // ---- phase 0: B frags + A frags (m 0..3), stage A of tile s+2, MFMA ----
    bf16x8 bfrag[4], afrag[4];
#pragma unroll
    for (int ni = 0; ni < 4; ni++) bfrag[ni] = *(const bf16x8*)(Bs_ + boff + ni * 1024);
#pragma unroll
    for (int mi = 0; mi < 4; mi++) afrag[mi] = *(const bf16x8*)(As_ + aoff + mi * 1024);
    if (s < 30) STAGE_A(s + 2, stg);
    __builtin_amdgcn_s_setprio(1);
#pragma unroll
    for (int mi = 0; mi < 4; mi++)
#pragma unroll
      for (int ni = 0; ni < 4; ni++)
        acc[mi][ni] = __builtin_amdgcn_mfma_f32_16x16x32_bf16(afrag[mi], bfrag[ni], acc[mi][ni], 0, 0, 0);
    __builtin_amdgcn_s_setprio(0);

    // ---- phase 1: A frags (m 4..7), stage B of tile s+2, MFMA ----
    bf16x8 afrag2[4];
#pragma unroll
    for (int mi = 0; mi < 4; mi++) afrag2[mi] = *(const bf16x8*)(As_ + aoff + (mi + 4) * 1024);
    if (s < 30) STAGE_B(s + 2, stg);
    __builtin_amdgcn_s_setprio(1);
#pragma unroll
    for (int mi = 0; mi < 4; mi++)
#pragma unroll
      for (int ni = 0; ni < 4; ni++)
        acc[mi + 4][ni] = __builtin_amdgcn_mfma_f32_16x16x32_bf16(afrag2[mi], bfrag[ni], acc[mi + 4][ni], 0, 0, 0);
    __builtin_amdgcn_s_setprio(0);

    stg = cur;                                  // next stage target = buf we just read
    cur = (cur == 49152) ? 0 : cur + 24576;     // advance read buf
  }
#undef STAGE_A
#undef STAGE_B

  // ---- fused epilogue: bias + RoPE (K half) + transposed scatter ----
  int col16 = r;
  float bv[4];
#pragma unroll
  for (int ni = 0; ni < 4; ni++) bv[ni] = bias[bn0 + wn * 64 + ni * 16 + col16];

  int cgrp = (bn0 >> 6) + wn;          // head-channel index 0..255, wave-uniform
  int is_k = (cgrp < 128);
  int h = cgrp & 127;
  size_t sec = is_k ? 0 : 4;           // s*4 (s=0 for K, 1 for V)

#pragma unroll
  for (int mi = 0; mi < 8; mi++) {
#pragma unroll
    for (int reg = 0; reg < 4; reg++) {
      int row = bm0 + wm * 128 + mi * 16 + q * 4 + reg;
      int bb = row >> 11;
      int n  = row & 2047;
      float* op = out + (((sec + bb) * 128 + h) * 2048 + (size_t)n) * 64;
      if (is_k) {
#pragma unroll
        for (int ni = 0; ni < 2; ni++) {
          int d = ni * 16 + col16;               // d in [0,32)
          float x0 = acc[mi][ni][reg]     + bv[ni];
          float x1 = acc[mi][ni + 2][reg] + bv[ni + 2];
          float sv = sin_t[row * 32 + d];
          float cv = cos_t[row * 32 + d];
          op[d]      = x0 * cv - x1 * sv;
          op[d + 32] = x0 * sv + x1 * cv;
        }
      } else {
#pragma unroll
        for (int ni = 0; ni < 4; ni++) {
          int d = ni * 16 + col16;
          op[d] = acc[mi][ni][reg] + bv[ni];
        }
      }
    }
  }
}

extern "C" void kernel_launch(void* const* d_in, const int* in_sizes, int n_in,
                              void* d_out, int out_size, void* d_ws, size_t ws_size,
                              hipStream_t stream) {
  const float* node = (const float*)d_in[0];   // [4][2048][1024]
  const float* mass = (const float*)d_in[1];   // [4][2048]
  const float* W    = (const float*)d_in[2];   // [1024][16384]
  const float* bias = (const float*)d_in[3];   // [16384]
  float* out = (float*)d_out;

  // workspace layout
  const size_t NODE_B  = (size_t)M_TOT * K_TOT * 2;       // 16.78 MB
  const size_t WT_B    = (size_t)N_TOT * K_TOT * 2;       // 33.55 MB
  const size_t SIN_B   = (size_t)M_TOT * 32 * 4;          // 1.05 MB
  if (ws_size < NODE_B + WT_B + 2 * SIN_B) return;        // fail visibly

  char* ws = (char*)d_ws;
  unsigned short* nodeB = (unsigned short*)ws;
  unsigned short* WtB   = (unsigned short*)(ws + NODE_B);
  float* sin_t = (float*)(ws + NODE_B + WT_B);
  float* cos_t = (float*)(ws + NODE_B + WT_B + SIN_B);

  // allow 72 KiB dynamic LDS for the GEMM (2 blocks/CU: 2 x 72 <= 160 KiB)
  (void)hipFuncSetAttribute((const void*)k_gemm256b,
                            hipFuncAttributeMaxDynamicSharedMemorySize, 73728);

  k_convert_node<<<1024, 256, 0, stream>>>(node, nodeB);
  k_transpose_w<<<dim3(N_TOT / 64, K_TOT / 64), 256, 0, stream>>>(W, WtB);
  k_sincos<<<(M_TOT * 32) / 256, 256, 0, stream>>>(mass, sin_t, cos_t);
  k_gemm256b<<<dim3((M_TOT / 256) * (N_TOT / 128)), dim3(256), 73728, stream>>>(
      nodeB, WtB, bias, sin_t, cos_t, out);
}

// Round 7
// 357.116 us; speedup vs baseline: 1.0722x; 1.0722x over previous
//
#include <hip/hip_runtime.h>
#include <stdint.h>

// Problem constants
#define M_TOT 8192      // B*N = 4*2048 rows
#define N_TOT 16384     // out_dim = 2*128*64
#define K_TOT 1024      // HIDDEN

typedef __bf16 bf16x8 __attribute__((ext_vector_type(8)));
typedef float f32x4 __attribute__((ext_vector_type(4)));

__device__ __forceinline__ unsigned short f2bf(float f) {
  unsigned int u = __float_as_uint(f);
  u = u + 0x7FFFu + ((u >> 16) & 1u);   // RNE
  return (unsigned short)(u >> 16);
}

__device__ __forceinline__ void gload_lds16(const void* g, void* l) {
  __builtin_amdgcn_global_load_lds(
      (const __attribute__((address_space(1))) unsigned int*)g,
      (__attribute__((address_space(3))) unsigned int*)l,
      16, 0, 0);
}

// ---- prep kernel 1: node f32 -> bf16, 32 elems/thread, 1024 blocks ----
__global__ __launch_bounds__(256) void k_convert_node(
    const float* __restrict__ src, unsigned short* __restrict__ dst) {
  size_t base = ((size_t)blockIdx.x * 256 + threadIdx.x) * 8;
#pragma unroll
  for (int it = 0; it < 4; it++) {
    size_t i = base + (size_t)it * (1024 * 256 * 8);
    float4 v0 = *(const float4*)(src + i);
    float4 v1 = *(const float4*)(src + i + 4);
    union { unsigned short u[8]; uint4 q; } r;
    r.u[0] = f2bf(v0.x); r.u[1] = f2bf(v0.y); r.u[2] = f2bf(v0.z); r.u[3] = f2bf(v0.w);
    r.u[4] = f2bf(v1.x); r.u[5] = f2bf(v1.y); r.u[6] = f2bf(v1.z); r.u[7] = f2bf(v1.w);
    *(uint4*)(dst + i) = r.q;
  }
}

// ---- prep kernel 2: W [K][O] f32 -> Wt [O][K] bf16, 64x64 tiles ----
__global__ __launch_bounds__(256) void k_transpose_w(
    const float* __restrict__ W, unsigned short* __restrict__ Wt) {
  __shared__ float tile[64][65];
  int o0 = blockIdx.x * 64;
  int k0 = blockIdx.y * 64;
  int t = threadIdx.x;
  int kr0 = t >> 4, c4 = t & 15;
#pragma unroll
  for (int i = 0; i < 4; i++) {
    int kr = kr0 + i * 16;
    float4 v = *(const float4*)&W[(size_t)(k0 + kr) * N_TOT + o0 + c4 * 4];
    tile[kr][c4 * 4 + 0] = v.x;
    tile[kr][c4 * 4 + 1] = v.y;
    tile[kr][c4 * 4 + 2] = v.z;
    tile[kr][c4 * 4 + 3] = v.w;
  }
  __syncthreads();
  int or0 = t >> 3, c8 = t & 7;
#pragma unroll
  for (int i = 0; i < 2; i++) {
    int orr = or0 + i * 32;
    union { unsigned short u[8]; uint4 q; } r;
#pragma unroll
    for (int j = 0; j < 8; j++) r.u[j] = f2bf(tile[c8 * 8 + j][orr]);
    *(uint4*)&Wt[(size_t)(o0 + orr) * K_TOT + k0 + c8 * 8] = r.q;
  }
}

// ---- prep kernel 3: sin/cos tables [row=8192][d=32] ----
__global__ __launch_bounds__(256) void k_sincos(
    const float* __restrict__ mass, float* __restrict__ sin_t, float* __restrict__ cos_t) {
  int t = blockIdx.x * 256 + threadIdx.x;   // 0..262143
  int row = t >> 5;
  int d = t & 31;
  float m = mass[row];
  float invf = expf(-0.28782313662425575f * (float)d);  // ln(10000)/32
  float ang = m * invf;
  float s, c;
  sincosf(ang, &s, &c);
  sin_t[t] = s;
  cos_t[t] = c;
}

// ---- main GEMM: 256x128 tile, BK=32, 4 waves (2x2), 3-deep pipelined LDS,
//      counted vmcnt (T3+T4), setprio (T5), 2 blocks/CU, conflict-free LDS
//      swizzle (T2, both-sides), and L2-locality superblock XCD swizzle:
//      XCD x owns bm in [4x,4x+4) (A slice 2 MB, L2-resident all kernel);
//      bn walked in super-tiles of 4bm x 8bn (B window 2 MB, 4x reuse). ----
__global__ __launch_bounds__(256, 2) void k_gemm256b(
    const unsigned short* __restrict__ A,    // [8192][1024] bf16
    const unsigned short* __restrict__ Bt,   // [16384][1024] bf16 (W^T)
    const float* __restrict__ bias,          // [16384]
    const float* __restrict__ sin_t,         // [8192][32]
    const float* __restrict__ cos_t,
    float* __restrict__ out)                 // [2][4][128][2048][64]
{
  extern __shared__ char smem[];   // 3 bufs x (As 16KB + Bs 8KB) = 72 KiB

  int tid  = threadIdx.x;
  int lane = tid & 63;
  int wid  = tid >> 6;      // 0..3
  int wm   = wid >> 1;      // 0..1  (M half: 128 rows)
  int wn   = wid & 1;       // 0..1  (N half: 64 cols)

  // L2-locality superblock swizzle (bijective; 4096 blocks, 4096 % 8 == 0):
  // XCD x = orig & 7 receives chunk position c = orig >> 3 (0..511).
  // super-tile st = c>>5 (16 of them): 4 bm x 8 bn blocks.
  int orig = blockIdx.x;
  int x   = orig & 7;
  int c   = orig >> 3;
  int st  = c >> 5;
  int w   = c & 31;
  int bm0 = (x * 4 + (w >> 3)) * 256;    // bm index: 4x + 0..3   (32 total)
  int bn0 = (st * 8 + (w & 7)) * 128;    // bn index: 8*st + 0..7 (128 total)

  // staging with inverse-swizzled source:
  // chunk c = j*256 + tid: rowp = c>>3, s' = c&7, v = s' ^ (rowp&7),
  // row = (rowp<<1)+(v>>2) = j*64 + (tid>>3)*2 + (v>>2), kslot = v&3.
  int sv   = (tid & 7) ^ ((tid >> 3) & 7);
  int arow = ((tid >> 3) << 1) + (sv >> 2);
  int kst  = sv & 3;
  const unsigned short* srcA = A  + (size_t)(bm0 + arow) * K_TOT + kst * 8;
  const unsigned short* srcB = Bt + (size_t)(bn0 + arow) * K_TOT + kst * 8;
  const size_t rs64 = (size_t)64 * K_TOT;

  // wave-uniform LDS staging bases: A at buf+0 (16KB), B at buf+16384 (8KB)
  int wofs = wid * 1024;

#define STAGE_A(s_, bo_) do { char* dA = smem + (bo_) + wofs; \
    const unsigned short* sa = srcA + (size_t)(s_) * 32; \
    gload_lds16(sa,            dA); \
    gload_lds16(sa + rs64,     dA + 4096); \
    gload_lds16(sa + 2 * rs64, dA + 8192); \
    gload_lds16(sa + 3 * rs64, dA + 12288); } while (0)
#define STAGE_B(s_, bo_) do { char* dB = smem + (bo_) + 16384 + wofs; \
    const unsigned short* sb = srcB + (size_t)(s_) * 32; \
    gload_lds16(sb,        dB); \
    gload_lds16(sb + rs64, dB + 4096); } while (0)

  // prologue: prefetch K-tiles 0,1 (12 loads in flight per wave)
  STAGE_A(0, 0); STAGE_B(0, 0);
  STAGE_A(1, 24576); STAGE_B(1, 24576);

  f32x4 acc[8][4] = {};

  int r = lane & 15;        // frag row/col within 16
  int q = lane >> 4;        // k-chunk 0..3 (8 bf16 each)
  // swizzled read offsets: lane reads (row = base + r, kslot = q)
  // byte = (row>>1)*128 + (((r&1)*4+q) ^ ((r>>1)&7))*16  (+ mi/ni * 1024)
  int sl   = (((r & 1) << 2) + q) ^ ((r >> 1) & 7);
  int aoff = wm * 8192 + (r >> 1) * 128 + sl * 16;   // byte offset in As
  int boff = wn * 4096 + (r >> 1) * 128 + sl * 16;   // byte offset in Bs

  int cur = 0;              // buf byte offsets rotate 0 -> 24576 -> 49152
  int stg = 49152;          // stage target for tile s+2 = buf (s-1)%3

  for (int s = 0; s < 32; ++s) {
    if (s < 31) { asm volatile("s_waitcnt vmcnt(6)" ::: "memory"); }
    else        { asm volatile("s_waitcnt vmcnt(0)" ::: "memory"); }
    __builtin_amdgcn_s_barrier();          // raw barrier: no vmcnt(0) drain
    __builtin_amdgcn_sched_barrier(0);     // keep ds_reads below the barrier

    const char* As_ = smem + cur;
    const char* Bs_ = As_ + 16384;

    // ---- phase 0: B frags + A frags (m 0..3), stage A of tile s+2, MFMA ----
    bf16x8 bfrag[4], afrag[4];
#pragma unroll
    for (int ni = 0; ni < 4; ni++) bfrag[ni] = *(const bf16x8*)(Bs_ + boff + ni * 1024);
#pragma unroll
    for (int mi = 0; mi < 4; mi++) afrag[mi] = *(const bf16x8*)(As_ + aoff + mi * 1024);
    if (s < 30) STAGE_A(s + 2, stg);
    __builtin_amdgcn_s_setprio(1);
#pragma unroll
    for (int mi = 0; mi < 4; mi++)
#pragma unroll
      for (int ni = 0; ni < 4; ni++)
        acc[mi][ni] = __builtin_amdgcn_mfma_f32_16x16x32_bf16(afrag[mi], bfrag[ni], acc[mi][ni], 0, 0, 0);
    __builtin_amdgcn_s_setprio(0);

    // ---- phase 1: A frags (m 4..7), stage B of tile s+2, MFMA ----
    bf16x8 afrag2[4];
#pragma unroll
    for (int mi = 0; mi < 4; mi++) afrag2[mi] = *(const bf16x8*)(As_ + aoff + (mi + 4) * 1024);
    if (s < 30) STAGE_B(s + 2, stg);
    __builtin_amdgcn_s_setprio(1);
#pragma unroll
    for (int mi = 0; mi < 4; mi++)
#pragma unroll
      for (int ni = 0; ni < 4; ni++)
        acc[mi + 4][ni] = __builtin_amdgcn_mfma_f32_16x16x32_bf16(afrag2[mi], bfrag[ni], acc[mi + 4][ni], 0, 0, 0);
    __builtin_amdgcn_s_setprio(0);

    stg = cur;                                  // next stage target = buf we just read
    cur = (cur == 49152) ? 0 : cur + 24576;     // advance read buf
  }
#undef STAGE_A
#undef STAGE_B

  // ---- fused epilogue: bias + RoPE (K half) + transposed scatter ----
  int col16 = r;
  float bv[4];
#pragma unroll
  for (int ni = 0; ni < 4; ni++) bv[ni] = bias[bn0 + wn * 64 + ni * 16 + col16];

  int cgrp = (bn0 >> 6) + wn;          // head-channel index 0..255, wave-uniform
  int is_k = (cgrp < 128);
  int h = cgrp & 127;
  size_t sec = is_k ? 0 : 4;           // s*4 (s=0 for K, 1 for V)

#pragma unroll
  for (int mi = 0; mi < 8; mi++) {
#pragma unroll
    for (int reg = 0; reg < 4; reg++) {
      int row = bm0 + wm * 128 + mi * 16 + q * 4 + reg;
      int bb = row >> 11;
      int n  = row & 2047;
      float* op = out + (((sec + bb) * 128 + h) * 2048 + (size_t)n) * 64;
      if (is_k) {
#pragma unroll
        for (int ni = 0; ni < 2; ni++) {
          int d = ni * 16 + col16;               // d in [0,32)
          float x0 = acc[mi][ni][reg]     + bv[ni];
          float x1 = acc[mi][ni + 2][reg] + bv[ni + 2];
          float sv = sin_t[row * 32 + d];
          float cv = cos_t[row * 32 + d];
          op[d]      = x0 * cv - x1 * sv;
          op[d + 32] = x0 * sv + x1 * cv;
        }
      } else {
#pragma unroll
        for (int ni = 0; ni < 4; ni++) {
          int d = ni * 16 + col16;
          op[d] = acc[mi][ni][reg] + bv[ni];
        }
      }
    }
  }
}

extern "C" void kernel_launch(void* const* d_in, const int* in_sizes, int n_in,
                              void* d_out, int out_size, void* d_ws, size_t ws_size,
                              hipStream_t stream) {
  const float* node = (const float*)d_in[0];   // [4][2048][1024]
  const float* mass = (const float*)d_in[1];   // [4][2048]
  const float* W    = (const float*)d_in[2];   // [1024][16384]
  const float* bias = (const float*)d_in[3];   // [16384]
  float* out = (float*)d_out;

  // workspace layout
  const size_t NODE_B  = (size_t)M_TOT * K_TOT * 2;       // 16.78 MB
  const size_t WT_B    = (size_t)N_TOT * K_TOT * 2;       // 33.55 MB
  const size_t SIN_B   = (size_t)M_TOT * 32 * 4;          // 1.05 MB
  if (ws_size < NODE_B + WT_B + 2 * SIN_B) return;        // fail visibly

  char* ws = (char*)d_ws;
  unsigned short* nodeB = (unsigned short*)ws;
  unsigned short* WtB   = (unsigned short*)(ws + NODE_B);
  float* sin_t = (float*)(ws + NODE_B + WT_B);
  float* cos_t = (float*)(ws + NODE_B + WT_B + SIN_B);

  // allow 72 KiB dynamic LDS for the GEMM (2 blocks/CU: 2 x 72 <= 160 KiB)
  (void)hipFuncSetAttribute((const void*)k_gemm256b,
                            hipFuncAttributeMaxDynamicSharedMemorySize, 73728);

  k_convert_node<<<1024, 256, 0, stream>>>(node, nodeB);
  k_transpose_w<<<dim3(N_TOT / 64, K_TOT / 64), 256, 0, stream>>>(W, WtB);
  k_sincos<<<(M_TOT * 32) / 256, 256, 0, stream>>>(mass, sin_t, cos_t);
  k_gemm256b<<<dim3((M_TOT / 256) * (N_TOT / 128)), dim3(256), 73728, stream>>>(
      nodeB, WtB, bias, sin_t, cos_t, out);
}

// Round 8
// 357.020 us; speedup vs baseline: 1.0725x; 1.0003x over previous
//
#include <hip/hip_runtime.h>
#include <stdint.h>

// Problem constants
#define M_TOT 8192      // B*N = 4*2048 rows
#define N_TOT 16384     // out_dim = 2*128*64
#define K_TOT 1024      // HIDDEN

typedef __bf16 bf16x8 __attribute__((ext_vector_type(8)));
typedef float f32x4 __attribute__((ext_vector_type(4)));

__device__ __forceinline__ unsigned short f2bf(float f) {
  unsigned int u = __float_as_uint(f);
  u = u + 0x7FFFu + ((u >> 16) & 1u);   // RNE
  return (unsigned short)(u >> 16);
}

__device__ __forceinline__ void gload_lds16(const void* g, void* l) {
  __builtin_amdgcn_global_load_lds(
      (const __attribute__((address_space(1))) unsigned int*)g,
      (__attribute__((address_space(3))) unsigned int*)l,
      16, 0, 0);
}

// ---- prep kernel 1: node f32 -> bf16, 32 elems/thread, 1024 blocks ----
__global__ __launch_bounds__(256) void k_convert_node(
    const float* __restrict__ src, unsigned short* __restrict__ dst) {
  size_t base = ((size_t)blockIdx.x * 256 + threadIdx.x) * 8;
#pragma unroll
  for (int it = 0; it < 4; it++) {
    size_t i = base + (size_t)it * (1024 * 256 * 8);
    float4 v0 = *(const float4*)(src + i);
    float4 v1 = *(const float4*)(src + i + 4);
    union { unsigned short u[8]; uint4 q; } r;
    r.u[0] = f2bf(v0.x); r.u[1] = f2bf(v0.y); r.u[2] = f2bf(v0.z); r.u[3] = f2bf(v0.w);
    r.u[4] = f2bf(v1.x); r.u[5] = f2bf(v1.y); r.u[6] = f2bf(v1.z); r.u[7] = f2bf(v1.w);
    *(uint4*)(dst + i) = r.q;
  }
}

// ---- prep kernel 2: W [K][O] f32 -> Wt [O][K] bf16, 64x64 tiles ----
__global__ __launch_bounds__(256) void k_transpose_w(
    const float* __restrict__ W, unsigned short* __restrict__ Wt) {
  __shared__ float tile[64][65];
  int o0 = blockIdx.x * 64;
  int k0 = blockIdx.y * 64;
  int t = threadIdx.x;
  int kr0 = t >> 4, c4 = t & 15;
#pragma unroll
  for (int i = 0; i < 4; i++) {
    int kr = kr0 + i * 16;
    float4 v = *(const float4*)&W[(size_t)(k0 + kr) * N_TOT + o0 + c4 * 4];
    tile[kr][c4 * 4 + 0] = v.x;
    tile[kr][c4 * 4 + 1] = v.y;
    tile[kr][c4 * 4 + 2] = v.z;
    tile[kr][c4 * 4 + 3] = v.w;
  }
  __syncthreads();
  int or0 = t >> 3, c8 = t & 7;
#pragma unroll
  for (int i = 0; i < 2; i++) {
    int orr = or0 + i * 32;
    union { unsigned short u[8]; uint4 q; } r;
#pragma unroll
    for (int j = 0; j < 8; j++) r.u[j] = f2bf(tile[c8 * 8 + j][orr]);
    *(uint4*)&Wt[(size_t)(o0 + orr) * K_TOT + k0 + c8 * 8] = r.q;
  }
}

// ---- prep kernel 3: sin/cos tables [row=8192][d=32] ----
__global__ __launch_bounds__(256) void k_sincos(
    const float* __restrict__ mass, float* __restrict__ sin_t, float* __restrict__ cos_t) {
  int t = blockIdx.x * 256 + threadIdx.x;   // 0..262143
  int row = t >> 5;
  int d = t & 31;
  float m = mass[row];
  float invf = expf(-0.28782313662425575f * (float)d);  // ln(10000)/32
  float ang = m * invf;
  float s, c;
  sincosf(ang, &s, &c);
  sin_t[t] = s;
  cos_t[t] = c;
}

// ---- main GEMM: 256x128 tile, BK=32, 4 waves (2x2), 3-deep pipelined LDS,
//      counted vmcnt (T3+T4), 2 blocks/CU, conflict-free LDS swizzle (T2),
//      L2-locality superblock XCD swizzle, and m201-style barrier-paired
//      phases: per K-iter 2 phases of {ds_reads || stage-issue -> barrier ->
//      lgkmcnt(0) -> setprio(1) 16-MFMA setprio(0)}. ----
__global__ __launch_bounds__(256, 2) void k_gemm256b(
    const unsigned short* __restrict__ A,    // [8192][1024] bf16
    const unsigned short* __restrict__ Bt,   // [16384][1024] bf16 (W^T)
    const float* __restrict__ bias,          // [16384]
    const float* __restrict__ sin_t,         // [8192][32]
    const float* __restrict__ cos_t,
    float* __restrict__ out)                 // [2][4][128][2048][64]
{
  extern __shared__ char smem[];   // 3 bufs x (As 16KB + Bs 8KB) = 72 KiB

  int tid  = threadIdx.x;
  int lane = tid & 63;
  int wid  = tid >> 6;      // 0..3
  int wm   = wid >> 1;      // 0..1  (M half: 128 rows)
  int wn   = wid & 1;       // 0..1  (N half: 64 cols)

  // L2-locality superblock swizzle (bijective; 4096 blocks, 4096 % 8 == 0):
  // XCD x = orig & 7 receives chunk position c = orig >> 3 (0..511).
  // super-tile st = c>>5 (16 of them): 4 bm x 8 bn blocks.
  int orig = blockIdx.x;
  int x   = orig & 7;
  int c   = orig >> 3;
  int st  = c >> 5;
  int w   = c & 31;
  int bm0 = (x * 4 + (w >> 3)) * 256;    // bm index: 4x + 0..3   (32 total)
  int bn0 = (st * 8 + (w & 7)) * 128;    // bn index: 8*st + 0..7 (128 total)

  // staging with inverse-swizzled source:
  // chunk c = j*256 + tid: rowp = c>>3, s' = c&7, v = s' ^ (rowp&7),
  // row = (rowp<<1)+(v>>2) = j*64 + (tid>>3)*2 + (v>>2), kslot = v&3.
  int sv   = (tid & 7) ^ ((tid >> 3) & 7);
  int arow = ((tid >> 3) << 1) + (sv >> 2);
  int kst  = sv & 3;
  const unsigned short* srcA = A  + (size_t)(bm0 + arow) * K_TOT + kst * 8;
  const unsigned short* srcB = Bt + (size_t)(bn0 + arow) * K_TOT + kst * 8;
  const size_t rs64 = (size_t)64 * K_TOT;

  // wave-uniform LDS staging bases: A at buf+0 (16KB), B at buf+16384 (8KB)
  int wofs = wid * 1024;

#define STAGE_A(s_, bo_) do { char* dA = smem + (bo_) + wofs; \
    const unsigned short* sa = srcA + (size_t)(s_) * 32; \
    gload_lds16(sa,            dA); \
    gload_lds16(sa + rs64,     dA + 4096); \
    gload_lds16(sa + 2 * rs64, dA + 8192); \
    gload_lds16(sa + 3 * rs64, dA + 12288); } while (0)
#define STAGE_B(s_, bo_) do { char* dB = smem + (bo_) + 16384 + wofs; \
    const unsigned short* sb = srcB + (size_t)(s_) * 32; \
    gload_lds16(sb,        dB); \
    gload_lds16(sb + rs64, dB + 4096); } while (0)

  // prologue: prefetch K-tiles 0,1 (12 loads in flight per wave)
  STAGE_A(0, 0); STAGE_B(0, 0);
  STAGE_A(1, 24576); STAGE_B(1, 24576);

  f32x4 acc[8][4] = {};

  int r = lane & 15;        // frag row/col within 16
  int q = lane >> 4;        // k-chunk 0..3 (8 bf16 each)
  // swizzled read offsets: lane reads (row = base + r, kslot = q)
  // byte = (row>>1)*128 + (((r&1)*4+q) ^ ((r>>1)&7))*16  (+ mi/ni * 1024)
  int sl   = (((r & 1) << 2) + q) ^ ((r >> 1) & 7);
  int aoff = wm * 8192 + (r >> 1) * 128 + sl * 16;   // byte offset in As
  int boff = wn * 4096 + (r >> 1) * 128 + sl * 16;   // byte offset in Bs

  int cur = 0;              // buf byte offsets rotate 0 -> 24576 -> 49152
  int stg = 49152;          // stage target for tile s+2 = buf (s-1)%3

  for (int s = 0; s < 32; ++s) {
    if (s < 31) { asm volatile("s_waitcnt vmcnt(6)" ::: "memory"); }
    else        { asm volatile("s_waitcnt vmcnt(0)" ::: "memory"); }
    __builtin_amdgcn_s_barrier();          // tile s resident for ALL waves
    __builtin_amdgcn_sched_barrier(0);     // keep ds_reads below the barrier

    const char* As_ = smem + cur;
    const char* Bs_ = As_ + 16384;

    // ---- phase 0: {B frags + A frags (m 0..3), stage A(s+2)} -> barrier
    //      -> lgkmcnt(0) -> MFMA cluster ----
    bf16x8 bfrag[4], afrag[4];
#pragma unroll
    for (int ni = 0; ni < 4; ni++) bfrag[ni] = *(const bf16x8*)(Bs_ + boff + ni * 1024);
#pragma unroll
    for (int mi = 0; mi < 4; mi++) afrag[mi] = *(const bf16x8*)(As_ + aoff + mi * 1024);
    if (s < 30) STAGE_A(s + 2, stg);
    __builtin_amdgcn_sched_barrier(0);     // pin reads+stage above the barrier
    __builtin_amdgcn_s_barrier();
    asm volatile("s_waitcnt lgkmcnt(0)" ::: "memory");
    __builtin_amdgcn_sched_barrier(0);
    __builtin_amdgcn_s_setprio(1);
#pragma unroll
    for (int mi = 0; mi < 4; mi++)
#pragma unroll
      for (int ni = 0; ni < 4; ni++)
        acc[mi][ni] = __builtin_amdgcn_mfma_f32_16x16x32_bf16(afrag[mi], bfrag[ni], acc[mi][ni], 0, 0, 0);
    __builtin_amdgcn_s_setprio(0);

    // ---- phase 1: {A frags (m 4..7), stage B(s+2)} -> barrier
    //      -> lgkmcnt(0) -> MFMA cluster ----
    bf16x8 afrag2[4];
#pragma unroll
    for (int mi = 0; mi < 4; mi++) afrag2[mi] = *(const bf16x8*)(As_ + aoff + (mi + 4) * 1024);
    if (s < 30) STAGE_B(s + 2, stg);
    __builtin_amdgcn_sched_barrier(0);     // pin reads+stage above the barrier
    __builtin_amdgcn_s_barrier();
    asm volatile("s_waitcnt lgkmcnt(0)" ::: "memory");
    __builtin_amdgcn_sched_barrier(0);
    __builtin_amdgcn_s_setprio(1);
#pragma unroll
    for (int mi = 0; mi < 4; mi++)
#pragma unroll
      for (int ni = 0; ni < 4; ni++)
        acc[mi + 4][ni] = __builtin_amdgcn_mfma_f32_16x16x32_bf16(afrag2[mi], bfrag[ni], acc[mi + 4][ni], 0, 0, 0);
    __builtin_amdgcn_s_setprio(0);

    stg = cur;                                  // next stage target = buf we just read
    cur = (cur == 49152) ? 0 : cur + 24576;     // advance read buf
  }
#undef STAGE_A
#undef STAGE_B

  // ---- fused epilogue: bias + RoPE (K half) + transposed scatter ----
  int col16 = r;
  float bv[4];
#pragma unroll
  for (int ni = 0; ni < 4; ni++) bv[ni] = bias[bn0 + wn * 64 + ni * 16 + col16];

  int cgrp = (bn0 >> 6) + wn;          // head-channel index 0..255, wave-uniform
  int is_k = (cgrp < 128);
  int h = cgrp & 127;
  size_t sec = is_k ? 0 : 4;           // s*4 (s=0 for K, 1 for V)

#pragma unroll
  for (int mi = 0; mi < 8; mi++) {
#pragma unroll
    for (int reg = 0; reg < 4; reg++) {
      int row = bm0 + wm * 128 + mi * 16 + q * 4 + reg;
      int bb = row >> 11;
      int n  = row & 2047;
      float* op = out + (((sec + bb) * 128 + h) * 2048 + (size_t)n) * 64;
      if (is_k) {
#pragma unroll
        for (int ni = 0; ni < 2; ni++) {
          int d = ni * 16 + col16;               // d in [0,32)
          float x0 = acc[mi][ni][reg]     + bv[ni];
          float x1 = acc[mi][ni + 2][reg] + bv[ni + 2];
          float sv = sin_t[row * 32 + d];
          float cv = cos_t[row * 32 + d];
          op[d]      = x0 * cv - x1 * sv;
          op[d + 32] = x0 * sv + x1 * cv;
        }
      } else {
#pragma unroll
        for (int ni = 0; ni < 4; ni++) {
          int d = ni * 16 + col16;
          op[d] = acc[mi][ni][reg] + bv[ni];
        }
      }
    }
  }
}

extern "C" void kernel_launch(void* const* d_in, const int* in_sizes, int n_in,
                              void* d_out, int out_size, void* d_ws, size_t ws_size,
                              hipStream_t stream) {
  const float* node = (const float*)d_in[0];   // [4][2048][1024]
  const float* mass = (const float*)d_in[1];   // [4][2048]
  const float* W    = (const float*)d_in[2];   // [1024][16384]
  const float* bias = (const float*)d_in[3];   // [16384]
  float* out = (float*)d_out;

  // workspace layout
  const size_t NODE_B  = (size_t)M_TOT * K_TOT * 2;       // 16.78 MB
  const size_t WT_B    = (size_t)N_TOT * K_TOT * 2;       // 33.55 MB
  const size_t SIN_B   = (size_t)M_TOT * 32 * 4;          // 1.05 MB
  if (ws_size < NODE_B + WT_B + 2 * SIN_B) return;        // fail visibly

  char* ws = (char*)d_ws;
  unsigned short* nodeB = (unsigned short*)ws;
  unsigned short* WtB   = (unsigned short*)(ws + NODE_B);
  float* sin_t = (float*)(ws + NODE_B + WT_B);
  float* cos_t = (float*)(ws + NODE_B + WT_B + SIN_B);

  // allow 72 KiB dynamic LDS for the GEMM (2 blocks/CU: 2 x 72 <= 160 KiB)
  (void)hipFuncSetAttribute((const void*)k_gemm256b,
                            hipFuncAttributeMaxDynamicSharedMemorySize, 73728);

  k_convert_node<<<1024, 256, 0, stream>>>(node, nodeB);
  k_transpose_w<<<dim3(N_TOT / 64, K_TOT / 64), 256, 0, stream>>>(W, WtB);
  k_sincos<<<(M_TOT * 32) / 256, 256, 0, stream>>>(mass, sin_t, cos_t);
  k_gemm256b<<<dim3((M_TOT / 256) * (N_TOT / 128)), dim3(256), 73728, stream>>>(
      nodeB, WtB, bias, sin_t, cos_t, out);
}